// Round 20
// baseline (64.103 us; speedup 1.0000x reference)
//
#include <hip/hip_runtime.h>
#include <math.h>

#define K_CODES 512
#define D_DIM   64
#define BM      512        // points per block (8 waves x 4 pt-tiles)
#define THREADS 512
#define LSTR    72         // padded presplit row stride (ushorts); row = 144 B
#define EPS_GAP 4e-5f      // certified: 2*(dref~8e-6 + dacc~2.2e-6)~2.05e-5, ~2x margin

// ws layout (bytes): [0,2048) norms | [2048) cnt | [4096,77824) eh presplit
// bf16 [512][72] | [77824,151552) el | [151552,..) worklist
#define WS_CNT_OFF  2048
#define WS_EH_OFF   4096
#define WS_EL_OFF   77824
#define WS_LIST_OFF 151552

typedef __attribute__((ext_vector_type(8))) short short8v;  // 8 bf16 (4 VGPRs)
typedef __attribute__((ext_vector_type(4))) float f32x4;

// ---------- FROZEN numerics (bit-exact vs np reference since R3) ----------
__device__ __forceinline__ float np_sumsq64(const float* zarr) {
    float L[16];
#pragma unroll
    for (int j = 0; j < 16; ++j)
        L[j] = __fadd_rn(
            __fadd_rn(__fmul_rn(zarr[j],      zarr[j]),
                      __fmul_rn(zarr[j + 16], zarr[j + 16])),
            __fadd_rn(__fmul_rn(zarr[j + 32], zarr[j + 32]),
                      __fmul_rn(zarr[j + 48], zarr[j + 48])));
    float m[8];
#pragma unroll
    for (int j = 0; j < 8; ++j) m[j] = __fadd_rn(L[j], L[j + 8]);
    float n4[4];
#pragma unroll
    for (int j = 0; j < 4; ++j) n4[j] = __fadd_rn(m[j], m[j + 4]);
    return __fadd_rn(__fadd_rn(n4[0], n4[2]), __fadd_rn(n4[1], n4[3]));
}

// ---------- bf16 split helpers (exact: x = hi + lo + r, |r| <= 2^-18|x|) ----------
__device__ __forceinline__ unsigned short f32_bf16_rne(float x) {
    unsigned int u = __float_as_uint(x);
    unsigned int r = (u + 0x7FFFu + ((u >> 16) & 1u)) >> 16;
    return (unsigned short)r;
}
__device__ __forceinline__ float bf16_f32(unsigned short h) {
    return __uint_as_float(((unsigned int)h) << 16);
}
__device__ __forceinline__ void split2(float x, unsigned short& h, unsigned short& l) {
    h = f32_bf16_rne(x);
    l = f32_bf16_rne(x - bf16_f32(h));   // x - hi is exact in fp32
}

// ---------- prep (4x parallel): norms + counter zero + presplit codebook ----------
__global__ __launch_bounds__(256)
void vq_prep_kernel(const float* __restrict__ cb, float* __restrict__ ws,
                    int do_split) {
    int g = blockIdx.x * blockDim.x + threadIdx.x;
    if (g == 0) *reinterpret_cast<int*>((char*)ws + WS_CNT_OFF) = 0;
    int k = g >> 2, q = g & 3;
    if (k >= K_CODES) return;
    const float* row = cb + (size_t)k * D_DIM;
    if (q == 0) {
        float e[D_DIM];
        const float4* p = reinterpret_cast<const float4*>(row);
#pragma unroll
        for (int i = 0; i < 16; ++i) {
            float4 v = p[i];
            e[4*i+0]=v.x; e[4*i+1]=v.y; e[4*i+2]=v.z; e[4*i+3]=v.w;
        }
        ws[k] = np_sumsq64(e);
    }
    if (do_split) {
        unsigned short* eh = reinterpret_cast<unsigned short*>((char*)ws + WS_EH_OFF)
                             + (size_t)k * LSTR;
        unsigned short* el = reinterpret_cast<unsigned short*>((char*)ws + WS_EL_OFF)
                             + (size_t)k * LSTR;
#pragma unroll
        for (int i = 16 * q; i < 16 * q + 16; ++i) {
            unsigned short h, l;
            split2(row[i], h, l);            // EXACT same split as always
            eh[i] = h; el[i] = l;
        }
        if (q == 3)
#pragma unroll
            for (int i = D_DIM; i < LSTR; ++i) { eh[i] = 0; el[i] = 0; }
    }
}

// ---------- epilogue helper: 4 scores vs (m1,m2,i1) ----------
// m2' = min(m2, max(m1, s)) [exact 2nd-min update]; m1' = min(m1, s).
// Value set is order-independent; i1 differs only on exact ties (flagged).
__device__ __forceinline__ void epi4(const f32x4& aA, const f32x4& aB,
                                     const float4& nr, int kg0,
                                     float& m1, float& m2, int& i1) {
    float nra[4] = {nr.x, nr.y, nr.z, nr.w};
#pragma unroll
    for (int r = 0; r < 4; ++r) {
        float dot = aA[r] + aB[r];                 // accuracy-only path
        float s   = fmaf(-2.0f, dot, nra[r]);
        bool lt1  = s < m1;
        m2 = fminf(m2, fmaxf(m1, s));
        i1 = lt1 ? (kg0 + r) : i1;
        m1 = fminf(m1, s);
    }
}

// One tile's fragment loads + 24-MFMA cluster into 8 named accs
// (4 ptiles x 2 K-halves): 8 independent dep-chains of DEPTH 3 (was 4x6).
#define TILE_COMPUTE(CT, A0,A1,A2,A3, B0,B1,B2,B3, NR, KG)                       \
  {                                                                              \
    const int ct_ = (CT);                                                        \
    int ar_ = (ct_ * 16 + c16) * LSTR + j * 8;                                   \
    short8v aeh0_ = *reinterpret_cast<const short8v*>(&ehS[ar_]);                \
    short8v aeh1_ = *reinterpret_cast<const short8v*>(&ehS[ar_ + 32]);           \
    short8v ael0_ = *reinterpret_cast<const short8v*>(&elS[ar_]);                \
    short8v ael1_ = *reinterpret_cast<const short8v*>(&elS[ar_ + 32]);           \
    NR = *reinterpret_cast<const float4*>(&nrmS[ct_ * 16 + j * 4]);              \
    KG = ct_ * 16 + j * 4;                                                       \
    A0 = ZERO4; A1 = ZERO4; A2 = ZERO4; A3 = ZERO4;                              \
    B0 = ZERO4; B1 = ZERO4; B2 = ZERO4; B3 = ZERO4;                              \
    __builtin_amdgcn_s_setprio(1);                                               \
    A0 = __builtin_amdgcn_mfma_f32_16x16x32_bf16(aeh0_, bzh[0][0], A0, 0,0,0);   \
    A1 = __builtin_amdgcn_mfma_f32_16x16x32_bf16(aeh0_, bzh[1][0], A1, 0,0,0);   \
    A2 = __builtin_amdgcn_mfma_f32_16x16x32_bf16(aeh0_, bzh[2][0], A2, 0,0,0);   \
    A3 = __builtin_amdgcn_mfma_f32_16x16x32_bf16(aeh0_, bzh[3][0], A3, 0,0,0);   \
    B0 = __builtin_amdgcn_mfma_f32_16x16x32_bf16(aeh1_, bzh[0][1], B0, 0,0,0);   \
    B1 = __builtin_amdgcn_mfma_f32_16x16x32_bf16(aeh1_, bzh[1][1], B1, 0,0,0);   \
    B2 = __builtin_amdgcn_mfma_f32_16x16x32_bf16(aeh1_, bzh[2][1], B2, 0,0,0);   \
    B3 = __builtin_amdgcn_mfma_f32_16x16x32_bf16(aeh1_, bzh[3][1], B3, 0,0,0);   \
    A0 = __builtin_amdgcn_mfma_f32_16x16x32_bf16(aeh0_, bzl[0][0], A0, 0,0,0);   \
    A1 = __builtin_amdgcn_mfma_f32_16x16x32_bf16(aeh0_, bzl[1][0], A1, 0,0,0);   \
    A2 = __builtin_amdgcn_mfma_f32_16x16x32_bf16(aeh0_, bzl[2][0], A2, 0,0,0);   \
    A3 = __builtin_amdgcn_mfma_f32_16x16x32_bf16(aeh0_, bzl[3][0], A3, 0,0,0);   \
    B0 = __builtin_amdgcn_mfma_f32_16x16x32_bf16(aeh1_, bzl[0][1], B0, 0,0,0);   \
    B1 = __builtin_amdgcn_mfma_f32_16x16x32_bf16(aeh1_, bzl[1][1], B1, 0,0,0);   \
    B2 = __builtin_amdgcn_mfma_f32_16x16x32_bf16(aeh1_, bzl[2][1], B2, 0,0,0);   \
    B3 = __builtin_amdgcn_mfma_f32_16x16x32_bf16(aeh1_, bzl[3][1], B3, 0,0,0);   \
    A0 = __builtin_amdgcn_mfma_f32_16x16x32_bf16(ael0_, bzh[0][0], A0, 0,0,0);   \
    A1 = __builtin_amdgcn_mfma_f32_16x16x32_bf16(ael0_, bzh[1][0], A1, 0,0,0);   \
    A2 = __builtin_amdgcn_mfma_f32_16x16x32_bf16(ael0_, bzh[2][0], A2, 0,0,0);   \
    A3 = __builtin_amdgcn_mfma_f32_16x16x32_bf16(ael0_, bzh[3][0], A3, 0,0,0);   \
    B0 = __builtin_amdgcn_mfma_f32_16x16x32_bf16(ael1_, bzh[0][1], B0, 0,0,0);   \
    B1 = __builtin_amdgcn_mfma_f32_16x16x32_bf16(ael1_, bzh[1][1], B1, 0,0,0);   \
    B2 = __builtin_amdgcn_mfma_f32_16x16x32_bf16(ael1_, bzh[2][1], B2, 0,0,0);   \
    B3 = __builtin_amdgcn_mfma_f32_16x16x32_bf16(ael1_, bzh[3][1], B3, 0,0,0);   \
    __builtin_amdgcn_s_setprio(0);                                               \
  }

// ---------- Pass 1 MONO+PIPE: whole codebook in LDS, 2-stage epilogue pipeline ----------
// R19 books: MFMA-busy 23K + VALU 20K vs 102K elapsed cyc/SIMD -> ~58Kcyc
// dependency stall. Fixes: (1) K-half-split accs: 8 dep-chains of depth 3;
// (2) even/odd NAMED register sets so tile t's epilogue VALU overlaps tile
// t+1's MFMA cluster (and vice versa) — no arrays, no copies (rule #20 safe).
__global__ __launch_bounds__(512)
void vq_pass1_mono(const float* __restrict__ z,
                   const unsigned short* __restrict__ eh_g,
                   const unsigned short* __restrict__ el_g,
                   const float* __restrict__ norms, int* __restrict__ out,
                   int* __restrict__ cnt, int* __restrict__ list, int cap, int n) {
    __shared__ __align__(16) unsigned short ehS[K_CODES * LSTR];  // 72 KiB
    __shared__ __align__(16) unsigned short elS[K_CODES * LSTR];  // 72 KiB
    __shared__ __align__(16) float nrmS[K_CODES];                 // 2 KiB

    const int tid  = threadIdx.x;
    const int l    = tid & 63;
    const int w    = tid >> 6;        // wave 0..7 -> pt-tiles {4w..4w+3}
    const int j    = l >> 4;          // k-chunk / C-row-group selector 0..3
    const int c16  = l & 15;
    const int base = blockIdx.x * BM;
    const f32x4 ZERO4 = {0.f, 0.f, 0.f, 0.f};

    // ---- stage ENTIRE presplit codebook once: 9x16B per thread per array ----
    {
        const char* esrc = (const char*)eh_g;
        const char* lsrc = (const char*)el_g;
#pragma unroll
        for (int r = 0; r < 9; ++r) {
            size_t off = ((size_t)tid + (size_t)r * THREADS) * 16;   // 73728 B
            __builtin_amdgcn_global_load_lds(
                (const __attribute__((address_space(1))) void*)(esrc + off),
                (__attribute__((address_space(3))) void*)((char*)ehS + off), 16, 0, 0);
            __builtin_amdgcn_global_load_lds(
                (const __attribute__((address_space(1))) void*)(lsrc + off),
                (__attribute__((address_space(3))) void*)((char*)elS + off), 16, 0, 0);
        }
        if (tid < K_CODES / 4)
            reinterpret_cast<float4*>(nrmS)[tid] =
                reinterpret_cast<const float4*>(norms)[tid];
    }

    // ---- z B-fragments direct from global, split in-register (overlaps DMA) ----
    short8v bzh[4][2], bzl[4][2];
#pragma unroll
    for (int p = 0; p < 4; ++p) {
        int row = base + (4 * w + p) * 16 + c16;
        if (row >= n) row = n - 1;
        const float* zp = z + (size_t)row * D_DIM + j * 8;
#pragma unroll
        for (int h = 0; h < 2; ++h) {
            float4 v0 = *reinterpret_cast<const float4*>(zp + h * 32);
            float4 v1 = *reinterpret_cast<const float4*>(zp + h * 32 + 4);
            unsigned short hh[8], ll[8];
            split2(v0.x, hh[0], ll[0]); split2(v0.y, hh[1], ll[1]);
            split2(v0.z, hh[2], ll[2]); split2(v0.w, hh[3], ll[3]);
            split2(v1.x, hh[4], ll[4]); split2(v1.y, hh[5], ll[5]);
            split2(v1.z, hh[6], ll[6]); split2(v1.w, hh[7], ll[7]);
            short8v th, tl;
#pragma unroll
            for (int i = 0; i < 8; ++i) { th[i] = (short)hh[i]; tl[i] = (short)ll[i]; }
            bzh[p][h] = th; bzl[p][h] = tl;
        }
    }

    __syncthreads();   // ONE barrier: staging DMA drained; none after this

    float m1[4] = {INFINITY, INFINITY, INFINITY, INFINITY};
    float m2[4] = {INFINITY, INFINITY, INFINITY, INFINITY};
    int   i1[4] = {0, 0, 0, 0};

    // even/odd pipelined sweep; per-wave tile rotation spreads LDS traffic
#define CTMAP(X) (((X) + 4 * w) & 31)
    f32x4 eA0,eA1,eA2,eA3,eB0,eB1,eB2,eB3;
    f32x4 oA0,oA1,oA2,oA3,oB0,oB1,oB2,oB3;
    float4 nrE, nrO; int kgE, kgO;

    TILE_COMPUTE(CTMAP(0), eA0,eA1,eA2,eA3, eB0,eB1,eB2,eB3, nrE, kgE);
#pragma unroll 1
    for (int i = 0; i < 15; ++i) {
        TILE_COMPUTE(CTMAP(2*i+1), oA0,oA1,oA2,oA3, oB0,oB1,oB2,oB3, nrO, kgO);
        epi4(eA0, eB0, nrE, kgE, m1[0], m2[0], i1[0]);
        epi4(eA1, eB1, nrE, kgE, m1[1], m2[1], i1[1]);
        epi4(eA2, eB2, nrE, kgE, m1[2], m2[2], i1[2]);
        epi4(eA3, eB3, nrE, kgE, m1[3], m2[3], i1[3]);
        TILE_COMPUTE(CTMAP(2*i+2), eA0,eA1,eA2,eA3, eB0,eB1,eB2,eB3, nrE, kgE);
        epi4(oA0, oB0, nrO, kgO, m1[0], m2[0], i1[0]);
        epi4(oA1, oB1, nrO, kgO, m1[1], m2[1], i1[1]);
        epi4(oA2, oB2, nrO, kgO, m1[2], m2[2], i1[2]);
        epi4(oA3, oB3, nrO, kgO, m1[3], m2[3], i1[3]);
    }
    TILE_COMPUTE(CTMAP(31), oA0,oA1,oA2,oA3, oB0,oB1,oB2,oB3, nrO, kgO);
    epi4(eA0, eB0, nrE, kgE, m1[0], m2[0], i1[0]);
    epi4(eA1, eB1, nrE, kgE, m1[1], m2[1], i1[1]);
    epi4(eA2, eB2, nrE, kgE, m1[2], m2[2], i1[2]);
    epi4(eA3, eB3, nrE, kgE, m1[3], m2[3], i1[3]);
    epi4(oA0, oB0, nrO, kgO, m1[0], m2[0], i1[0]);
    epi4(oA1, oB1, nrO, kgO, m1[1], m2[1], i1[1]);
    epi4(oA2, oB2, nrO, kgO, m1[2], m2[2], i1[2]);
    epi4(oA3, oB3, nrO, kgO, m1[3], m2[3], i1[3]);
#undef CTMAP

    // ---- butterfly merge (pure shfl) + compacting store ----
#pragma unroll
    for (int p = 0; p < 4; ++p) {
        float a1 = m1[p], a2 = m2[p]; int ai = i1[p];
#pragma unroll
        for (int off = 16; off <= 32; off <<= 1) {
            float o1 = __shfl_xor(a1, off, 64);
            float o2 = __shfl_xor(a2, off, 64);
            int   oi = __shfl_xor(ai, off, 64);
            float hi = fmaxf(a1, o1);
            bool take = o1 < a1;                 // ties keep own (tie => flagged anyway)
            ai = take ? oi : ai;
            a1 = take ? o1 : a1;
            a2 = fminf(hi, fminf(a2, o2));
        }
        int  ptg    = base + (4 * w + p) * 16 + c16;
        bool writer = (j == 0) && (ptg < n);
        bool flag   = writer && (a2 - a1 <= EPS_GAP);
        unsigned long long m = __ballot(flag);
        int abase = 0;
        if (m) {
            int leader = __ffsll(m) - 1;
            if (l == leader) abase = atomicAdd(cnt, __popcll(m));
            abase = __shfl(abase, leader, 64);
        }
        if (writer) {
            int val = ai;
            if (flag) {
                int rank = __popcll(m & ((1ull << l) - 1ull));
                int slot = abase + rank;
                if (slot < cap) list[slot] = ptg;       // worklist path
                else            val |= (int)0x80000000; // overflow fallback
            }
            out[ptg] = val;
        }
    }
}

// ---------- Pass 1 LEGACY (R13 verbatim, BM=128): used only if ws too small ----------
__global__ __launch_bounds__(256)
void vq_pass1_legacy(const float* __restrict__ z, const float* __restrict__ cb,
                     const float* __restrict__ norms, int* __restrict__ out,
                     int* __restrict__ cnt, int* __restrict__ list, int cap, int n) {
    __shared__ unsigned short zhS[128 * LSTR];
    __shared__ unsigned short zlS[128 * LSTR];
    __shared__ unsigned short ehS[128 * LSTR];
    __shared__ unsigned short elS[128 * LSTR];
    __shared__ float nrmL[128];

    const int tid  = threadIdx.x;
    const int l    = tid & 63;
    const int w    = tid >> 6;
    const int j    = l >> 4;
    const int c16  = l & 15;
    const int base = blockIdx.x * 128;

    const float4* z4 = reinterpret_cast<const float4*>(z);
#pragma unroll
    for (int rep = 0; rep < 8; ++rep) {
        int flat = rep * 256 + tid;
        int pt   = flat >> 4;
        int dblk = flat & 15;
        int gp = base + pt; if (gp >= n) gp = n - 1;
        float4 v = z4[(size_t)gp * 16 + dblk];
        ushort4 h, lo;
        split2(v.x, h.x, lo.x); split2(v.y, h.y, lo.y);
        split2(v.z, h.z, lo.z); split2(v.w, h.w, lo.w);
        *reinterpret_cast<ushort4*>(&zhS[pt * LSTR + dblk * 4]) = h;
        *reinterpret_cast<ushort4*>(&zlS[pt * LSTR + dblk * 4]) = lo;
    }
    __syncthreads();

    short8v bzh[2][2], bzl[2][2];
#pragma unroll
    for (int p = 0; p < 2; ++p) {
        int pr = ((2 * w + p) * 16 + c16) * LSTR;
#pragma unroll
        for (int h = 0; h < 2; ++h) {
            int off = pr + h * 32 + j * 8;
            bzh[p][h] = *reinterpret_cast<const short8v*>(&zhS[off]);
            bzl[p][h] = *reinterpret_cast<const short8v*>(&zlS[off]);
        }
    }

    float m1[2] = {INFINITY, INFINITY};
    float m2[2] = {INFINITY, INFINITY};
    int   i1[2] = {0, 0};

    for (int c = 0; c < 4; ++c) {
        __syncthreads();
        const float4* cb4 = reinterpret_cast<const float4*>(cb);
#pragma unroll
        for (int rep = 0; rep < 8; ++rep) {
            int flat = rep * 256 + tid;
            int code = flat >> 4;
            int dblk = flat & 15;
            float4 v = cb4[(size_t)(c * 128 + code) * 16 + dblk];
            ushort4 h, lo;
            split2(v.x, h.x, lo.x); split2(v.y, h.y, lo.y);
            split2(v.z, h.z, lo.z); split2(v.w, h.w, lo.w);
            *reinterpret_cast<ushort4*>(&ehS[code * LSTR + dblk * 4]) = h;
            *reinterpret_cast<ushort4*>(&elS[code * LSTR + dblk * 4]) = lo;
        }
        if (tid < 32)
            reinterpret_cast<float4*>(nrmL)[tid] =
                reinterpret_cast<const float4*>(norms)[c * 32 + tid];
        __syncthreads();

#pragma unroll
        for (int ct = 0; ct < 8; ++ct) {
            int ar = (ct * 16 + c16) * LSTR + j * 8;
            short8v aeh0 = *reinterpret_cast<const short8v*>(&ehS[ar]);
            short8v aeh1 = *reinterpret_cast<const short8v*>(&ehS[ar + 32]);
            short8v ael0 = *reinterpret_cast<const short8v*>(&elS[ar]);
            short8v ael1 = *reinterpret_cast<const short8v*>(&elS[ar + 32]);
            float4 nr = *reinterpret_cast<const float4*>(&nrmL[ct * 16 + j * 4]);
            float nra[4] = {nr.x, nr.y, nr.z, nr.w};
            int kg0 = c * 128 + ct * 16 + j * 4;
#pragma unroll
            for (int p = 0; p < 2; ++p) {
                f32x4 acc = {0.f, 0.f, 0.f, 0.f};
                acc = __builtin_amdgcn_mfma_f32_16x16x32_bf16(aeh0, bzh[p][0], acc, 0, 0, 0);
                acc = __builtin_amdgcn_mfma_f32_16x16x32_bf16(aeh1, bzh[p][1], acc, 0, 0, 0);
                acc = __builtin_amdgcn_mfma_f32_16x16x32_bf16(aeh0, bzl[p][0], acc, 0, 0, 0);
                acc = __builtin_amdgcn_mfma_f32_16x16x32_bf16(aeh1, bzl[p][1], acc, 0, 0, 0);
                acc = __builtin_amdgcn_mfma_f32_16x16x32_bf16(ael0, bzh[p][0], acc, 0, 0, 0);
                acc = __builtin_amdgcn_mfma_f32_16x16x32_bf16(ael1, bzh[p][1], acc, 0, 0, 0);
#pragma unroll
                for (int r = 0; r < 4; ++r) {
                    float s = fmaf(-2.0f, acc[r], nra[r]);
                    int kg = kg0 + r;
                    bool lt1 = s < m1[p];
                    float nm2 = lt1 ? m1[p] : fminf(s, m2[p]);
                    i1[p] = lt1 ? kg : i1[p];
                    m1[p] = lt1 ? s : m1[p];
                    m2[p] = nm2;
                }
            }
        }
    }

#pragma unroll
    for (int p = 0; p < 2; ++p) {
        float a1 = m1[p], a2 = m2[p]; int ai = i1[p];
#pragma unroll
        for (int off = 16; off <= 32; off <<= 1) {
            float o1 = __shfl_xor(a1, off, 64);
            float o2 = __shfl_xor(a2, off, 64);
            int   oi = __shfl_xor(ai, off, 64);
            float hi = fmaxf(a1, o1);
            bool take = o1 < a1;
            ai = take ? oi : ai;
            a1 = take ? o1 : a1;
            a2 = fminf(hi, fminf(a2, o2));
        }
        int  ptg    = base + (2 * w + p) * 16 + c16;
        bool writer = (j == 0) && (ptg < n);
        bool flag   = writer && (a2 - a1 <= EPS_GAP);
        unsigned long long m = __ballot(flag);
        int abase = 0;
        if (m) {
            int leader = __ffsll(m) - 1;
            if (l == leader) abase = atomicAdd(cnt, __popcll(m));
            abase = __shfl(abase, leader, 64);
        }
        if (writer) {
            int val = ai;
            if (flag) {
                int rank = __popcll(m & ((1ull << l) - 1ull));
                int slot = abase + rank;
                if (slot < cap) list[slot] = ptg;
                else            val |= (int)0x80000000;
            }
            out[ptg] = val;
        }
    }
}

// ---------- Pass 2: one BLOCK (4 waves, 2 codes/lane) per flagged point ----------
__global__ __launch_bounds__(256)
void vq_cleanup_kernel(const float* __restrict__ z, const float* __restrict__ cb,
                       const float* __restrict__ norms,
                       const int* __restrict__ cnt, const int* __restrict__ list,
                       int cap, int* __restrict__ out, int n) {
    __shared__ float rbv[4];
    __shared__ int   rbi[4];
    const int tid  = threadIdx.x;
    const int lane = tid & 63;
    const int wv   = tid >> 6;

    int total = *cnt;
    int lim   = total < cap ? total : cap;

    for (int i = blockIdx.x; i < lim; i += gridDim.x) {
        int pt = list[i];
        float zr[D_DIM];
        const float4* zp = reinterpret_cast<const float4*>(z + (size_t)pt * D_DIM);
#pragma unroll
        for (int g = 0; g < 16; ++g) {
            float4 q = zp[g];
            zr[4*g+0]=q.x; zr[4*g+1]=q.y; zr[4*g+2]=q.z; zr[4*g+3]=q.w;
        }
        const float sz = np_sumsq64(zr);           // FROZEN tree
        float best = INFINITY; int bi = 0x7FFFFFFF;
#pragma unroll 1
        for (int r = 0; r < 2; ++r) {              // 2 codes/thread, sequential
            int k = tid * 2 + r;
            const float4* e4 = reinterpret_cast<const float4*>(cb) + ((size_t)k << 4);
            float a = 0.f;
#pragma unroll
            for (int g = 0; g < 16; ++g) {         // FROZEN ascending-d chain
                float4 q = e4[g];
                a = fmaf(zr[4*g+0], q.x, a);
                a = fmaf(zr[4*g+1], q.y, a);
                a = fmaf(zr[4*g+2], q.z, a);
                a = fmaf(zr[4*g+3], q.w, a);
            }
            float s = __fadd_rn(__fsub_rn(sz, __fmul_rn(2.0f, a)), norms[k]);
            if (s < best || (s == best && k < bi)) { best = s; bi = k; }
        }
#pragma unroll
        for (int off = 1; off < 64; off <<= 1) {   // wave (value,index) reduce
            float os = __shfl_xor(best, off, 64);
            int   ok = __shfl_xor(bi, off, 64);
            if (os < best || (os == best && ok < bi)) { best = os; bi = ok; }
        }
        if (lane == 0) { rbv[wv] = best; rbi[wv] = bi; }
        __syncthreads();
        if (tid == 0) {
            float b = rbv[0]; int id = rbi[0];
#pragma unroll
            for (int q = 1; q < 4; ++q) {
                float v = rbv[q]; int vi = rbi[q];
                if (v < b || (v == b && vi < id)) { b = v; id = vi; }
            }
            out[pt] = id;
        }
        __syncthreads();
    }

    // overflow fallback: wave-per-point scan of out[] for bit-31 flags
    if (total > cap) {
        const int wid    = (blockIdx.x * blockDim.x + tid) >> 6;
        const int nwaves = (gridDim.x * blockDim.x) >> 6;
        for (int b = wid * 64; b < n; b += nwaves * 64) {
            int t = b + lane;
            int v = (t < n) ? out[t] : 0;
            unsigned long long m = __ballot(v < 0);
            while (m) {
                int bb = __ffsll(m) - 1;
                m &= m - 1ull;
                int pt = b + bb;
                float zr[D_DIM];
                const float4* zp = reinterpret_cast<const float4*>(z + (size_t)pt * D_DIM);
#pragma unroll
                for (int g = 0; g < 16; ++g) {
                    float4 q = zp[g];
                    zr[4*g+0]=q.x; zr[4*g+1]=q.y; zr[4*g+2]=q.z; zr[4*g+3]=q.w;
                }
                const float sz = np_sumsq64(zr);
                float best = INFINITY; int bi = 0x7FFFFFFF;
#pragma unroll 1
                for (int r = 0; r < 8; ++r) {
                    const float4* e4 = reinterpret_cast<const float4*>(cb) +
                                       ((size_t)(lane * 8 + r) << 4);
                    float a = 0.f;
#pragma unroll
                    for (int g = 0; g < 16; ++g) {
                        float4 q = e4[g];
                        a = fmaf(zr[4*g+0], q.x, a);
                        a = fmaf(zr[4*g+1], q.y, a);
                        a = fmaf(zr[4*g+2], q.z, a);
                        a = fmaf(zr[4*g+3], q.w, a);
                    }
                    float s = __fadd_rn(__fsub_rn(sz, __fmul_rn(2.0f, a)),
                                        norms[lane * 8 + r]);
                    if (s < best) { best = s; bi = lane * 8 + r; }
                }
#pragma unroll
                for (int off = 1; off < 64; off <<= 1) {
                    float os = __shfl_xor(best, off, 64);
                    int   ok = __shfl_xor(bi, off, 64);
                    if (os < best || (os == best && ok < bi)) { best = os; bi = ok; }
                }
                if (lane == 0) out[pt] = bi;
            }
        }
    }
}

extern "C" void kernel_launch(void* const* d_in, const int* in_sizes, int n_in,
                              void* d_out, int out_size, void* d_ws, size_t ws_size,
                              hipStream_t stream) {
    const float* z  = (const float*)d_in[0];
    const float* cb = (const float*)d_in[1];
    int n = in_sizes[0] / D_DIM;           // 131072 points
    float* norms = (float*)d_ws;
    int*   cnt   = (int*)((char*)d_ws + WS_CNT_OFF);
    int* out = (int*)d_out;

    bool fast = ws_size >= (size_t)WS_LIST_OFF + 4096;
    vq_prep_kernel<<<(4 * K_CODES + 255) / 256, 256, 0, stream>>>(cb, norms, fast ? 1 : 0);

    if (fast) {
        const unsigned short* eh = (const unsigned short*)((char*)d_ws + WS_EH_OFF);
        const unsigned short* el = (const unsigned short*)((char*)d_ws + WS_EL_OFF);
        int* list = (int*)((char*)d_ws + WS_LIST_OFF);
        int  cap  = (int)((ws_size - WS_LIST_OFF) / 4);
        vq_pass1_mono<<<(n + BM - 1) / BM, THREADS, 0, stream>>>(
            z, eh, el, norms, out, cnt, list, cap, n);
        vq_cleanup_kernel<<<2048, 256, 0, stream>>>(z, cb, norms, cnt, list, cap, out, n);
    } else {
        int* list = (int*)d_ws + 513;
        int  cap  = (int)(ws_size / 4) - 513; if (cap < 0) cap = 0;
        vq_pass1_legacy<<<(n + 127) / 128, 256, 0, stream>>>(
            z, cb, norms, out, cnt, list, cap, n);
        vq_cleanup_kernel<<<2048, 256, 0, stream>>>(z, cb, norms, cnt, list, cap, out, n);
    }
}

// Round 21
// 63.773 us; speedup vs baseline: 1.0052x; 1.0052x over previous
//
#include <hip/hip_runtime.h>
#include <math.h>

#define K_CODES 512
#define D_DIM   64
#define BM      512        // points per block (8 waves x 4 pt-tiles)
#define THREADS 512
#define LSTR    72         // padded presplit row stride (ushorts); row = 144 B
#define CLS     65         // cleanup fp32 LDS row stride (2-way-free scalar reads)
#define EPS_GAP 6e-5f      // budget: 2*(dref 8e-6 + dacc 2.2e-6) + pack 1.6e-5 ~ 3.7e-5

// ws layout (bytes): [0,2048) norms | [2048) cnt | [4096,77824) eh presplit
// bf16 [512][72] | [77824,151552) el | [151552,..) worklist
#define WS_CNT_OFF  2048
#define WS_EH_OFF   4096
#define WS_EL_OFF   77824
#define WS_LIST_OFF 151552

typedef __attribute__((ext_vector_type(8))) short short8v;  // 8 bf16 (4 VGPRs)
typedef __attribute__((ext_vector_type(4))) float f32x4;

// ---------- FROZEN numerics (bit-exact vs np reference since R3) ----------
__device__ __forceinline__ float np_sumsq64(const float* zarr) {
    float L[16];
#pragma unroll
    for (int j = 0; j < 16; ++j)
        L[j] = __fadd_rn(
            __fadd_rn(__fmul_rn(zarr[j],      zarr[j]),
                      __fmul_rn(zarr[j + 16], zarr[j + 16])),
            __fadd_rn(__fmul_rn(zarr[j + 32], zarr[j + 32]),
                      __fmul_rn(zarr[j + 48], zarr[j + 48])));
    float m[8];
#pragma unroll
    for (int j = 0; j < 8; ++j) m[j] = __fadd_rn(L[j], L[j + 8]);
    float n4[4];
#pragma unroll
    for (int j = 0; j < 4; ++j) n4[j] = __fadd_rn(m[j], m[j + 4]);
    return __fadd_rn(__fadd_rn(n4[0], n4[2]), __fadd_rn(n4[1], n4[3]));
}

// ---------- bf16 split helpers (exact: x = hi + lo + r, |r| <= 2^-18|x|) ----------
__device__ __forceinline__ unsigned short f32_bf16_rne(float x) {
    unsigned int u = __float_as_uint(x);
    unsigned int r = (u + 0x7FFFu + ((u >> 16) & 1u)) >> 16;
    return (unsigned short)r;
}
__device__ __forceinline__ float bf16_f32(unsigned short h) {
    return __uint_as_float(((unsigned int)h) << 16);
}
__device__ __forceinline__ void split2(float x, unsigned short& h, unsigned short& l) {
    h = f32_bf16_rne(x);
    l = f32_bf16_rne(x - bf16_f32(h));   // x - hi is exact in fp32
}

// ---------- prep (4x parallel): norms + counter zero + presplit codebook ----------
__global__ __launch_bounds__(256)
void vq_prep_kernel(const float* __restrict__ cb, float* __restrict__ ws,
                    int do_split) {
    int g = blockIdx.x * blockDim.x + threadIdx.x;
    if (g == 0) *reinterpret_cast<int*>((char*)ws + WS_CNT_OFF) = 0;
    int k = g >> 2, q = g & 3;
    if (k >= K_CODES) return;
    const float* row = cb + (size_t)k * D_DIM;
    if (q == 0) {
        float e[D_DIM];
        const float4* p = reinterpret_cast<const float4*>(row);
#pragma unroll
        for (int i = 0; i < 16; ++i) {
            float4 v = p[i];
            e[4*i+0]=v.x; e[4*i+1]=v.y; e[4*i+2]=v.z; e[4*i+3]=v.w;
        }
        ws[k] = np_sumsq64(e);
    }
    if (do_split) {
        unsigned short* eh = reinterpret_cast<unsigned short*>((char*)ws + WS_EH_OFF)
                             + (size_t)k * LSTR;
        unsigned short* el = reinterpret_cast<unsigned short*>((char*)ws + WS_EL_OFF)
                             + (size_t)k * LSTR;
#pragma unroll
        for (int i = 16 * q; i < 16 * q + 16; ++i) {
            unsigned short h, l;
            split2(row[i], h, l);            // EXACT same split as always
            eh[i] = h; el[i] = l;
        }
        if (q == 3)
#pragma unroll
            for (int i = D_DIM; i < LSTR; ++i) { eh[i] = 0; el[i] = 0; }
    }
}

// ---------- Pass 1 MONO v2: norm-in-C MFMA + (-2z) splits + packed value/index ----------
// R20 books (VALUBusy at face value): VALU ~40Kcyc/SIMD co-dominant with MFMA
// 30Kcyc; the gap to my ~16Kcyc source count = accumulator management (32 acc
// zero-init writes + score add/fmaf/cmp/cndmask per tile). Deletions:
//  (1) C-init = norm vector, z scaled by EXACT -2 in the bf16 split ->
//      acc_final IS the score (no zero-init, no add, no fmaf);
//  (2) packed value+index pk = (s & ~0x1FF) | k -> single fmin chain carries
//      the argmin (no cmp, no cndmask); pack noise <= ~8e-6 absorbed by EPS.
// Order-independence: (m1,m2) = (min, 2nd-min) of a value set; all ties /
// near-ties land in the flagged set -> exact FROZEN cleanup resolves them.
__global__ __launch_bounds__(512)
void vq_pass1_mono(const float* __restrict__ z,
                   const unsigned short* __restrict__ eh_g,
                   const unsigned short* __restrict__ el_g,
                   const float* __restrict__ norms, int* __restrict__ out,
                   int* __restrict__ cnt, int* __restrict__ list, int cap, int n) {
    __shared__ __align__(16) unsigned short ehS[K_CODES * LSTR];  // 72 KiB
    __shared__ __align__(16) unsigned short elS[K_CODES * LSTR];  // 72 KiB
    __shared__ __align__(16) float nrmS[K_CODES];                 // 2 KiB

    const int tid  = threadIdx.x;
    const int l    = tid & 63;
    const int w    = tid >> 6;        // wave 0..7 -> pt-tiles {4w..4w+3}
    const int j    = l >> 4;          // k-chunk / C-row-group selector 0..3
    const int c16  = l & 15;
    const int j4   = j * 4;
    const int base = blockIdx.x * BM;

    // ---- stage ENTIRE presplit codebook once: 9x16B per thread per array ----
    {
        const char* esrc = (const char*)eh_g;
        const char* lsrc = (const char*)el_g;
#pragma unroll
        for (int r = 0; r < 9; ++r) {
            size_t off = ((size_t)tid + (size_t)r * THREADS) * 16;   // 73728 B
            __builtin_amdgcn_global_load_lds(
                (const __attribute__((address_space(1))) void*)(esrc + off),
                (__attribute__((address_space(3))) void*)((char*)ehS + off), 16, 0, 0);
            __builtin_amdgcn_global_load_lds(
                (const __attribute__((address_space(1))) void*)(lsrc + off),
                (__attribute__((address_space(3))) void*)((char*)elS + off), 16, 0, 0);
        }
        if (tid < K_CODES / 4)
            reinterpret_cast<float4*>(nrmS)[tid] =
                reinterpret_cast<const float4*>(norms)[tid];
    }

    // ---- z B-fragments: load, scale by EXACT -2, split in-register ----
    short8v bzh[4][2], bzl[4][2];
#pragma unroll
    for (int p = 0; p < 4; ++p) {
        int row = base + (4 * w + p) * 16 + c16;
        if (row >= n) row = n - 1;
        const float* zp = z + (size_t)row * D_DIM + j * 8;
#pragma unroll
        for (int h = 0; h < 2; ++h) {
            float4 v0 = *reinterpret_cast<const float4*>(zp + h * 32);
            float4 v1 = *reinterpret_cast<const float4*>(zp + h * 32 + 4);
            unsigned short hh[8], ll[8];
            split2(-2.0f * v0.x, hh[0], ll[0]); split2(-2.0f * v0.y, hh[1], ll[1]);
            split2(-2.0f * v0.z, hh[2], ll[2]); split2(-2.0f * v0.w, hh[3], ll[3]);
            split2(-2.0f * v1.x, hh[4], ll[4]); split2(-2.0f * v1.y, hh[5], ll[5]);
            split2(-2.0f * v1.z, hh[6], ll[6]); split2(-2.0f * v1.w, hh[7], ll[7]);
            short8v th, tl;
#pragma unroll
            for (int i = 0; i < 8; ++i) { th[i] = (short)hh[i]; tl[i] = (short)ll[i]; }
            bzh[p][h] = th; bzl[p][h] = tl;
        }
    }

    __syncthreads();   // ONE barrier: staging DMA drained; none after this

    float m1[4] = {INFINITY, INFINITY, INFINITY, INFINITY};
    float m2[4] = {INFINITY, INFINITY, INFINITY, INFINITY};

#pragma unroll 4
    for (int cti = 0; cti < 32; ++cti) {
        const int ct = (cti + 4 * w) & 31;    // per-wave rotation (wave-uniform)
        int ar = (ct * 16 + c16) * LSTR + j * 8;
        short8v aeh0 = *reinterpret_cast<const short8v*>(&ehS[ar]);
        short8v aeh1 = *reinterpret_cast<const short8v*>(&ehS[ar + 32]);
        short8v ael0 = *reinterpret_cast<const short8v*>(&elS[ar]);
        short8v ael1 = *reinterpret_cast<const short8v*>(&elS[ar + 32]);
        float4 nr = *reinterpret_cast<const float4*>(&nrmS[ct * 16 + j4]);
        f32x4 nrv = {nr.x, nr.y, nr.z, nr.w};

        f32x4 acc[4];
#pragma unroll
        for (int p = 0; p < 4; ++p) acc[p] = nrv;   // C-init = norms (no zeroing)
        __builtin_amdgcn_s_setprio(1);
#pragma unroll
        for (int p = 0; p < 4; ++p) {
            acc[p] = __builtin_amdgcn_mfma_f32_16x16x32_bf16(aeh0, bzh[p][0], acc[p], 0, 0, 0);
            acc[p] = __builtin_amdgcn_mfma_f32_16x16x32_bf16(aeh1, bzh[p][1], acc[p], 0, 0, 0);
            acc[p] = __builtin_amdgcn_mfma_f32_16x16x32_bf16(aeh0, bzl[p][0], acc[p], 0, 0, 0);
            acc[p] = __builtin_amdgcn_mfma_f32_16x16x32_bf16(aeh1, bzl[p][1], acc[p], 0, 0, 0);
            acc[p] = __builtin_amdgcn_mfma_f32_16x16x32_bf16(ael0, bzh[p][0], acc[p], 0, 0, 0);
            acc[p] = __builtin_amdgcn_mfma_f32_16x16x32_bf16(ael1, bzh[p][1], acc[p], 0, 0, 0);
        }
        __builtin_amdgcn_s_setprio(0);

        // packed epilogue: pk carries the code index in mantissa low 9 bits
        const unsigned kb = (unsigned)(ct * 16) | (unsigned)j4;
#pragma unroll
        for (int p = 0; p < 4; ++p) {
#pragma unroll
            for (int r = 0; r < 4; ++r) {
                unsigned bits = (__float_as_uint(acc[p][r]) & 0xFFFFFE00u)
                                | (kb + (unsigned)r);
                float pk = __uint_as_float(bits);
                m2[p] = fminf(m2[p], fmaxf(m1[p], pk));
                m1[p] = fminf(m1[p], pk);
            }
        }
    }

    // ---- butterfly merge on packed values + compacting store ----
#pragma unroll
    for (int p = 0; p < 4; ++p) {
        float a1 = m1[p], a2 = m2[p];
#pragma unroll
        for (int off = 16; off <= 32; off <<= 1) {
            float o1 = __shfl_xor(a1, off, 64);
            float o2 = __shfl_xor(a2, off, 64);
            a2 = fminf(fminf(a2, o2), fmaxf(a1, o1));
            a1 = fminf(a1, o1);
        }
        int  ptg    = base + (4 * w + p) * 16 + c16;
        bool writer = (j == 0) && (ptg < n);
        bool flag   = writer && (a2 - a1 <= EPS_GAP);
        unsigned long long m = __ballot(flag);
        int abase = 0;
        if (m) {
            int leader = __ffsll(m) - 1;
            if (l == leader) abase = atomicAdd(cnt, __popcll(m));
            abase = __shfl(abase, leader, 64);
        }
        if (writer) {
            int val = (int)(__float_as_uint(a1) & 0x1FFu);   // unpack argmin
            if (flag) {
                int rank = __popcll(m & ((1ull << l) - 1ull));
                int slot = abase + rank;
                if (slot < cap) list[slot] = ptg;       // worklist path
                else            val |= (int)0x80000000; // overflow fallback
            }
            out[ptg] = val;
        }
    }
}

// ---------- Pass 1 LEGACY (R13 verbatim, BM=128): used only if ws too small ----------
__global__ __launch_bounds__(256)
void vq_pass1_legacy(const float* __restrict__ z, const float* __restrict__ cb,
                     const float* __restrict__ norms, int* __restrict__ out,
                     int* __restrict__ cnt, int* __restrict__ list, int cap, int n) {
    __shared__ unsigned short zhS[128 * LSTR];
    __shared__ unsigned short zlS[128 * LSTR];
    __shared__ unsigned short ehS[128 * LSTR];
    __shared__ unsigned short elS[128 * LSTR];
    __shared__ float nrmL[128];

    const int tid  = threadIdx.x;
    const int l    = tid & 63;
    const int w    = tid >> 6;
    const int j    = l >> 4;
    const int c16  = l & 15;
    const int base = blockIdx.x * 128;

    const float4* z4 = reinterpret_cast<const float4*>(z);
#pragma unroll
    for (int rep = 0; rep < 8; ++rep) {
        int flat = rep * 256 + tid;
        int pt   = flat >> 4;
        int dblk = flat & 15;
        int gp = base + pt; if (gp >= n) gp = n - 1;
        float4 v = z4[(size_t)gp * 16 + dblk];
        ushort4 h, lo;
        split2(v.x, h.x, lo.x); split2(v.y, h.y, lo.y);
        split2(v.z, h.z, lo.z); split2(v.w, h.w, lo.w);
        *reinterpret_cast<ushort4*>(&zhS[pt * LSTR + dblk * 4]) = h;
        *reinterpret_cast<ushort4*>(&zlS[pt * LSTR + dblk * 4]) = lo;
    }
    __syncthreads();

    short8v bzh[2][2], bzl[2][2];
#pragma unroll
    for (int p = 0; p < 2; ++p) {
        int pr = ((2 * w + p) * 16 + c16) * LSTR;
#pragma unroll
        for (int h = 0; h < 2; ++h) {
            int off = pr + h * 32 + j * 8;
            bzh[p][h] = *reinterpret_cast<const short8v*>(&zhS[off]);
            bzl[p][h] = *reinterpret_cast<const short8v*>(&zlS[off]);
        }
    }

    float m1[2] = {INFINITY, INFINITY};
    float m2[2] = {INFINITY, INFINITY};
    int   i1[2] = {0, 0};

    for (int c = 0; c < 4; ++c) {
        __syncthreads();
        const float4* cb4 = reinterpret_cast<const float4*>(cb);
#pragma unroll
        for (int rep = 0; rep < 8; ++rep) {
            int flat = rep * 256 + tid;
            int code = flat >> 4;
            int dblk = flat & 15;
            float4 v = cb4[(size_t)(c * 128 + code) * 16 + dblk];
            ushort4 h, lo;
            split2(v.x, h.x, lo.x); split2(v.y, h.y, lo.y);
            split2(v.z, h.z, lo.z); split2(v.w, h.w, lo.w);
            *reinterpret_cast<ushort4*>(&ehS[code * LSTR + dblk * 4]) = h;
            *reinterpret_cast<ushort4*>(&elS[code * LSTR + dblk * 4]) = lo;
        }
        if (tid < 32)
            reinterpret_cast<float4*>(nrmL)[tid] =
                reinterpret_cast<const float4*>(norms)[c * 32 + tid];
        __syncthreads();

#pragma unroll
        for (int ct = 0; ct < 8; ++ct) {
            int ar = (ct * 16 + c16) * LSTR + j * 8;
            short8v aeh0 = *reinterpret_cast<const short8v*>(&ehS[ar]);
            short8v aeh1 = *reinterpret_cast<const short8v*>(&ehS[ar + 32]);
            short8v ael0 = *reinterpret_cast<const short8v*>(&elS[ar]);
            short8v ael1 = *reinterpret_cast<const short8v*>(&elS[ar + 32]);
            float4 nr = *reinterpret_cast<const float4*>(&nrmL[ct * 16 + j * 4]);
            float nra[4] = {nr.x, nr.y, nr.z, nr.w};
            int kg0 = c * 128 + ct * 16 + j * 4;
#pragma unroll
            for (int p = 0; p < 2; ++p) {
                f32x4 acc = {0.f, 0.f, 0.f, 0.f};
                acc = __builtin_amdgcn_mfma_f32_16x16x32_bf16(aeh0, bzh[p][0], acc, 0, 0, 0);
                acc = __builtin_amdgcn_mfma_f32_16x16x32_bf16(aeh1, bzh[p][1], acc, 0, 0, 0);
                acc = __builtin_amdgcn_mfma_f32_16x16x32_bf16(aeh0, bzl[p][0], acc, 0, 0, 0);
                acc = __builtin_amdgcn_mfma_f32_16x16x32_bf16(aeh1, bzl[p][1], acc, 0, 0, 0);
                acc = __builtin_amdgcn_mfma_f32_16x16x32_bf16(ael0, bzh[p][0], acc, 0, 0, 0);
                acc = __builtin_amdgcn_mfma_f32_16x16x32_bf16(ael1, bzh[p][1], acc, 0, 0, 0);
#pragma unroll
                for (int r = 0; r < 4; ++r) {
                    float s = fmaf(-2.0f, acc[r], nra[r]);
                    int kg = kg0 + r;
                    bool lt1 = s < m1[p];
                    float nm2 = lt1 ? m1[p] : fminf(s, m2[p]);
                    i1[p] = lt1 ? kg : i1[p];
                    m1[p] = lt1 ? s : m1[p];
                    m2[p] = nm2;
                }
            }
        }
    }

#pragma unroll
    for (int p = 0; p < 2; ++p) {
        float a1 = m1[p], a2 = m2[p]; int ai = i1[p];
#pragma unroll
        for (int off = 16; off <= 32; off <<= 1) {
            float o1 = __shfl_xor(a1, off, 64);
            float o2 = __shfl_xor(a2, off, 64);
            int   oi = __shfl_xor(ai, off, 64);
            float hi = fmaxf(a1, o1);
            bool take = o1 < a1;
            ai = take ? oi : ai;
            a1 = take ? o1 : a1;
            a2 = fminf(hi, fminf(a2, o2));
        }
        int  ptg    = base + (2 * w + p) * 16 + c16;
        bool writer = (j == 0) && (ptg < n);
        bool flag   = writer && (a2 - a1 <= EPS_GAP);
        unsigned long long m = __ballot(flag);
        int abase = 0;
        if (m) {
            int leader = __ffsll(m) - 1;
            if (l == leader) abase = atomicAdd(cnt, __popcll(m));
            abase = __shfl(abase, leader, 64);
        }
        if (writer) {
            int val = ai;
            if (flag) {
                int rank = __popcll(m & ((1ull << l) - 1ull));
                int slot = abase + rank;
                if (slot < cap) list[slot] = ptg;
                else            val |= (int)0x80000000;
            }
            out[ptg] = val;
        }
    }
}

// ---------- Pass 2 v2: fp32 codebook staged in LDS; block-per-flagged-point ----------
// Old cleanup re-read the 128KB codebook from L2 per point (2500 pts x 128KB
// = 320MB = ~9.3us floor). Now: 256 blocks each stage the EXACT fp32 cb once
// (133KB LDS, 65-float padded rows -> (t + d) % 32 bank pattern = 2-way free
// on scalar reads), then grid-stride the worklist. FROZEN chain bit-identical.
__global__ __launch_bounds__(256)
void vq_cleanup_kernel(const float* __restrict__ z, const float* __restrict__ cb,
                       const float* __restrict__ norms,
                       const int* __restrict__ cnt, const int* __restrict__ list,
                       int cap, int* __restrict__ out, int n) {
    __shared__ float cbS[K_CODES * CLS];   // 133.1 KB exact fp32 codebook
    __shared__ float rbv[4];
    __shared__ int   rbi[4];
    const int tid  = threadIdx.x;
    const int lane = tid & 63;
    const int wv   = tid >> 6;

    // stage exact fp32 codebook into padded LDS rows (bit-preserving)
    {
        const float4* cb4 = reinterpret_cast<const float4*>(cb);
        for (int i = tid; i < K_CODES * 16; i += 256) {
            float4 v = cb4[i];
            int row = i >> 4, col = (i & 15) * 4;
            float* d = &cbS[row * CLS + col];
            d[0] = v.x; d[1] = v.y; d[2] = v.z; d[3] = v.w;
        }
    }
    __syncthreads();

    int total = *cnt;
    int lim   = total < cap ? total : cap;

    for (int i = blockIdx.x; i < lim; i += gridDim.x) {
        int pt = list[i];
        float zr[D_DIM];
        const float4* zp = reinterpret_cast<const float4*>(z + (size_t)pt * D_DIM);
#pragma unroll
        for (int g = 0; g < 16; ++g) {
            float4 q = zp[g];
            zr[4*g+0]=q.x; zr[4*g+1]=q.y; zr[4*g+2]=q.z; zr[4*g+3]=q.w;
        }
        const float sz = np_sumsq64(zr);           // FROZEN tree
        float best = INFINITY; int bi = 0x7FFFFFFF;
#pragma unroll 1
        for (int rr = 0; rr < 2; ++rr) {           // 2 codes/thread, sequential
            int k = tid + rr * 256;
            const float* e = &cbS[k * CLS];
            float a = 0.f;
#pragma unroll
            for (int d = 0; d < D_DIM; ++d)        // FROZEN ascending-d chain
                a = fmaf(zr[d], e[d], a);
            float s = __fadd_rn(__fsub_rn(sz, __fmul_rn(2.0f, a)), norms[k]);
            if (s < best || (s == best && k < bi)) { best = s; bi = k; }
        }
#pragma unroll
        for (int off = 1; off < 64; off <<= 1) {   // wave (value,index) reduce
            float os = __shfl_xor(best, off, 64);
            int   ok = __shfl_xor(bi, off, 64);
            if (os < best || (os == best && ok < bi)) { best = os; bi = ok; }
        }
        if (lane == 0) { rbv[wv] = best; rbi[wv] = bi; }
        __syncthreads();
        if (tid == 0) {
            float b = rbv[0]; int id = rbi[0];
#pragma unroll
            for (int q = 1; q < 4; ++q) {
                float v = rbv[q]; int vi = rbi[q];
                if (v < b || (v == b && vi < id)) { b = v; id = vi; }
            }
            out[pt] = id;
        }
        __syncthreads();
    }

    // overflow fallback: wave-per-point scan of out[] for bit-31 flags (cbS exact)
    if (total > cap) {
        const int wid    = (blockIdx.x * blockDim.x + tid) >> 6;
        const int nwaves = (gridDim.x * blockDim.x) >> 6;
        for (int b = wid * 64; b < n; b += nwaves * 64) {
            int t = b + lane;
            int v = (t < n) ? out[t] : 0;
            unsigned long long m = __ballot(v < 0);
            while (m) {
                int bb = __ffsll(m) - 1;
                m &= m - 1ull;
                int pt = b + bb;
                float zr[D_DIM];
                const float4* zp = reinterpret_cast<const float4*>(z + (size_t)pt * D_DIM);
#pragma unroll
                for (int g = 0; g < 16; ++g) {
                    float4 q = zp[g];
                    zr[4*g+0]=q.x; zr[4*g+1]=q.y; zr[4*g+2]=q.z; zr[4*g+3]=q.w;
                }
                const float sz = np_sumsq64(zr);
                float best = INFINITY; int bi = 0x7FFFFFFF;
#pragma unroll 1
                for (int r = 0; r < 8; ++r) {
                    int k = lane * 8 + r;
                    const float* e = &cbS[k * CLS];
                    float a = 0.f;
#pragma unroll
                    for (int d = 0; d < D_DIM; ++d)
                        a = fmaf(zr[d], e[d], a);
                    float s = __fadd_rn(__fsub_rn(sz, __fmul_rn(2.0f, a)), norms[k]);
                    if (s < best) { best = s; bi = k; }
                }
#pragma unroll
                for (int off = 1; off < 64; off <<= 1) {
                    float os = __shfl_xor(best, off, 64);
                    int   ok = __shfl_xor(bi, off, 64);
                    if (os < best || (os == best && ok < bi)) { best = os; bi = ok; }
                }
                if (lane == 0) out[pt] = bi;
            }
        }
    }
}

extern "C" void kernel_launch(void* const* d_in, const int* in_sizes, int n_in,
                              void* d_out, int out_size, void* d_ws, size_t ws_size,
                              hipStream_t stream) {
    const float* z  = (const float*)d_in[0];
    const float* cb = (const float*)d_in[1];
    int n = in_sizes[0] / D_DIM;           // 131072 points
    float* norms = (float*)d_ws;
    int*   cnt   = (int*)((char*)d_ws + WS_CNT_OFF);
    int* out = (int*)d_out;

    bool fast = ws_size >= (size_t)WS_LIST_OFF + 4096;
    vq_prep_kernel<<<(4 * K_CODES + 255) / 256, 256, 0, stream>>>(cb, norms, fast ? 1 : 0);

    if (fast) {
        const unsigned short* eh = (const unsigned short*)((char*)d_ws + WS_EH_OFF);
        const unsigned short* el = (const unsigned short*)((char*)d_ws + WS_EL_OFF);
        int* list = (int*)((char*)d_ws + WS_LIST_OFF);
        int  cap  = (int)((ws_size - WS_LIST_OFF) / 4);
        vq_pass1_mono<<<(n + BM - 1) / BM, THREADS, 0, stream>>>(
            z, eh, el, norms, out, cnt, list, cap, n);
        vq_cleanup_kernel<<<256, 256, 0, stream>>>(z, cb, norms, cnt, list, cap, out, n);
    } else {
        int* list = (int*)d_ws + 513;
        int  cap  = (int)(ws_size / 4) - 513; if (cap < 0) cap = 0;
        vq_pass1_legacy<<<(n + 127) / 128, 256, 0, stream>>>(
            z, cb, norms, out, cnt, list, cap, n);
        vq_cleanup_kernel<<<256, 256, 0, stream>>>(z, cb, norms, cnt, list, cap, out, n);
    }
}

// Round 22
// 63.222 us; speedup vs baseline: 1.0139x; 1.0087x over previous
//
#include <hip/hip_runtime.h>
#include <math.h>

#define K_CODES 512
#define D_DIM   64
#define BM      512        // points per block (8 waves x 4 pt-tiles)
#define THREADS 512
#define LSTR    72         // padded presplit row stride (ushorts); row = 144 B
#define EPS_GAP 4.5e-5f    // budget: 2*(dref 8e-6 + dacc 2.2e-6) + pack 7.6e-6 = 2.8e-5

// ws layout (bytes): [0,2048) norms | [2048) cnt | [4096,77824) eh presplit
// bf16 [512][72] | [77824,151552) el | [151552,..) worklist
#define WS_CNT_OFF  2048
#define WS_EH_OFF   4096
#define WS_EL_OFF   77824
#define WS_LIST_OFF 151552

typedef __attribute__((ext_vector_type(8))) short short8v;  // 8 bf16 (4 VGPRs)
typedef __attribute__((ext_vector_type(4))) float f32x4;

// ---------- FROZEN numerics (bit-exact vs np reference since R3) ----------
__device__ __forceinline__ float np_sumsq64(const float* zarr) {
    float L[16];
#pragma unroll
    for (int j = 0; j < 16; ++j)
        L[j] = __fadd_rn(
            __fadd_rn(__fmul_rn(zarr[j],      zarr[j]),
                      __fmul_rn(zarr[j + 16], zarr[j + 16])),
            __fadd_rn(__fmul_rn(zarr[j + 32], zarr[j + 32]),
                      __fmul_rn(zarr[j + 48], zarr[j + 48])));
    float m[8];
#pragma unroll
    for (int j = 0; j < 8; ++j) m[j] = __fadd_rn(L[j], L[j + 8]);
    float n4[4];
#pragma unroll
    for (int j = 0; j < 4; ++j) n4[j] = __fadd_rn(m[j], m[j + 4]);
    return __fadd_rn(__fadd_rn(n4[0], n4[2]), __fadd_rn(n4[1], n4[3]));
}

// ---------- bf16 split helpers (exact: x = hi + lo + r, |r| <= 2^-18|x|) ----------
__device__ __forceinline__ unsigned short f32_bf16_rne(float x) {
    unsigned int u = __float_as_uint(x);
    unsigned int r = (u + 0x7FFFu + ((u >> 16) & 1u)) >> 16;
    return (unsigned short)r;
}
__device__ __forceinline__ float bf16_f32(unsigned short h) {
    return __uint_as_float(((unsigned int)h) << 16);
}
__device__ __forceinline__ void split2(float x, unsigned short& h, unsigned short& l) {
    h = f32_bf16_rne(x);
    l = f32_bf16_rne(x - bf16_f32(h));   // x - hi is exact in fp32
}

// ---------- prep (4x parallel): norms + counter zero + presplit codebook ----------
__global__ __launch_bounds__(256)
void vq_prep_kernel(const float* __restrict__ cb, float* __restrict__ ws,
                    int do_split) {
    int g = blockIdx.x * blockDim.x + threadIdx.x;
    if (g == 0) *reinterpret_cast<int*>((char*)ws + WS_CNT_OFF) = 0;
    int k = g >> 2, q = g & 3;
    if (k >= K_CODES) return;
    const float* row = cb + (size_t)k * D_DIM;
    if (q == 0) {
        float e[D_DIM];
        const float4* p = reinterpret_cast<const float4*>(row);
#pragma unroll
        for (int i = 0; i < 16; ++i) {
            float4 v = p[i];
            e[4*i+0]=v.x; e[4*i+1]=v.y; e[4*i+2]=v.z; e[4*i+3]=v.w;
        }
        ws[k] = np_sumsq64(e);
    }
    if (do_split) {
        unsigned short* eh = reinterpret_cast<unsigned short*>((char*)ws + WS_EH_OFF)
                             + (size_t)k * LSTR;
        unsigned short* el = reinterpret_cast<unsigned short*>((char*)ws + WS_EL_OFF)
                             + (size_t)k * LSTR;
#pragma unroll
        for (int i = 16 * q; i < 16 * q + 16; ++i) {
            unsigned short h, l;
            split2(row[i], h, l);            // EXACT same split as always
            eh[i] = h; el[i] = l;
        }
        if (q == 3)
#pragma unroll
            for (int i = D_DIM; i < LSTR; ++i) { eh[i] = 0; el[i] = 0; }
    }
}

// ---------- Pass 1 MONO v2 (R21, plateaued at ~42us after 8 structural A/Bs):
// whole presplit codebook in LDS, one barrier, norm-in-C MFMA, (-2z) splits,
// packed value/index epilogue. EPS tightened 6e-5 -> 4.5e-5 (pack noise
// re-derived: 512*ULP(0.12) = 7.6e-6, budget 2.8e-5, margin 1.6x) to cut
// the flag count ~25-30% (R21 WRITE showed ~16K flags at 6e-5).
__global__ __launch_bounds__(512)
void vq_pass1_mono(const float* __restrict__ z,
                   const unsigned short* __restrict__ eh_g,
                   const unsigned short* __restrict__ el_g,
                   const float* __restrict__ norms, int* __restrict__ out,
                   int* __restrict__ cnt, int* __restrict__ list, int cap, int n) {
    __shared__ __align__(16) unsigned short ehS[K_CODES * LSTR];  // 72 KiB
    __shared__ __align__(16) unsigned short elS[K_CODES * LSTR];  // 72 KiB
    __shared__ __align__(16) float nrmS[K_CODES];                 // 2 KiB

    const int tid  = threadIdx.x;
    const int l    = tid & 63;
    const int w    = tid >> 6;        // wave 0..7 -> pt-tiles {4w..4w+3}
    const int j    = l >> 4;          // k-chunk / C-row-group selector 0..3
    const int c16  = l & 15;
    const int j4   = j * 4;
    const int base = blockIdx.x * BM;

    // ---- stage ENTIRE presplit codebook once: 9x16B per thread per array ----
    {
        const char* esrc = (const char*)eh_g;
        const char* lsrc = (const char*)el_g;
#pragma unroll
        for (int r = 0; r < 9; ++r) {
            size_t off = ((size_t)tid + (size_t)r * THREADS) * 16;   // 73728 B
            __builtin_amdgcn_global_load_lds(
                (const __attribute__((address_space(1))) void*)(esrc + off),
                (__attribute__((address_space(3))) void*)((char*)ehS + off), 16, 0, 0);
            __builtin_amdgcn_global_load_lds(
                (const __attribute__((address_space(1))) void*)(lsrc + off),
                (__attribute__((address_space(3))) void*)((char*)elS + off), 16, 0, 0);
        }
        if (tid < K_CODES / 4)
            reinterpret_cast<float4*>(nrmS)[tid] =
                reinterpret_cast<const float4*>(norms)[tid];
    }

    // ---- z B-fragments: load, scale by EXACT -2, split in-register ----
    short8v bzh[4][2], bzl[4][2];
#pragma unroll
    for (int p = 0; p < 4; ++p) {
        int row = base + (4 * w + p) * 16 + c16;
        if (row >= n) row = n - 1;
        const float* zp = z + (size_t)row * D_DIM + j * 8;
#pragma unroll
        for (int h = 0; h < 2; ++h) {
            float4 v0 = *reinterpret_cast<const float4*>(zp + h * 32);
            float4 v1 = *reinterpret_cast<const float4*>(zp + h * 32 + 4);
            unsigned short hh[8], ll[8];
            split2(-2.0f * v0.x, hh[0], ll[0]); split2(-2.0f * v0.y, hh[1], ll[1]);
            split2(-2.0f * v0.z, hh[2], ll[2]); split2(-2.0f * v0.w, hh[3], ll[3]);
            split2(-2.0f * v1.x, hh[4], ll[4]); split2(-2.0f * v1.y, hh[5], ll[5]);
            split2(-2.0f * v1.z, hh[6], ll[6]); split2(-2.0f * v1.w, hh[7], ll[7]);
            short8v th, tl;
#pragma unroll
            for (int i = 0; i < 8; ++i) { th[i] = (short)hh[i]; tl[i] = (short)ll[i]; }
            bzh[p][h] = th; bzl[p][h] = tl;
        }
    }

    __syncthreads();   // ONE barrier: staging DMA drained; none after this

    float m1[4] = {INFINITY, INFINITY, INFINITY, INFINITY};
    float m2[4] = {INFINITY, INFINITY, INFINITY, INFINITY};

#pragma unroll 4
    for (int cti = 0; cti < 32; ++cti) {
        const int ct = (cti + 4 * w) & 31;    // per-wave rotation (wave-uniform)
        int ar = (ct * 16 + c16) * LSTR + j * 8;
        short8v aeh0 = *reinterpret_cast<const short8v*>(&ehS[ar]);
        short8v aeh1 = *reinterpret_cast<const short8v*>(&ehS[ar + 32]);
        short8v ael0 = *reinterpret_cast<const short8v*>(&elS[ar]);
        short8v ael1 = *reinterpret_cast<const short8v*>(&elS[ar + 32]);
        float4 nr = *reinterpret_cast<const float4*>(&nrmS[ct * 16 + j4]);
        f32x4 nrv = {nr.x, nr.y, nr.z, nr.w};

        f32x4 acc[4];
#pragma unroll
        for (int p = 0; p < 4; ++p) acc[p] = nrv;   // C-init = norms (no zeroing)
        __builtin_amdgcn_s_setprio(1);
#pragma unroll
        for (int p = 0; p < 4; ++p) {
            acc[p] = __builtin_amdgcn_mfma_f32_16x16x32_bf16(aeh0, bzh[p][0], acc[p], 0, 0, 0);
            acc[p] = __builtin_amdgcn_mfma_f32_16x16x32_bf16(aeh1, bzh[p][1], acc[p], 0, 0, 0);
            acc[p] = __builtin_amdgcn_mfma_f32_16x16x32_bf16(aeh0, bzl[p][0], acc[p], 0, 0, 0);
            acc[p] = __builtin_amdgcn_mfma_f32_16x16x32_bf16(aeh1, bzl[p][1], acc[p], 0, 0, 0);
            acc[p] = __builtin_amdgcn_mfma_f32_16x16x32_bf16(ael0, bzh[p][0], acc[p], 0, 0, 0);
            acc[p] = __builtin_amdgcn_mfma_f32_16x16x32_bf16(ael1, bzh[p][1], acc[p], 0, 0, 0);
        }
        __builtin_amdgcn_s_setprio(0);

        // packed epilogue: pk carries the code index in mantissa low 9 bits
        const unsigned kb = (unsigned)(ct * 16) | (unsigned)j4;
#pragma unroll
        for (int p = 0; p < 4; ++p) {
#pragma unroll
            for (int r = 0; r < 4; ++r) {
                unsigned bits = (__float_as_uint(acc[p][r]) & 0xFFFFFE00u)
                                | (kb + (unsigned)r);
                float pk = __uint_as_float(bits);
                m2[p] = fminf(m2[p], fmaxf(m1[p], pk));
                m1[p] = fminf(m1[p], pk);
            }
        }
    }

    // ---- butterfly merge on packed values + compacting store ----
#pragma unroll
    for (int p = 0; p < 4; ++p) {
        float a1 = m1[p], a2 = m2[p];
#pragma unroll
        for (int off = 16; off <= 32; off <<= 1) {
            float o1 = __shfl_xor(a1, off, 64);
            float o2 = __shfl_xor(a2, off, 64);
            a2 = fminf(fminf(a2, o2), fmaxf(a1, o1));
            a1 = fminf(a1, o1);
        }
        int  ptg    = base + (4 * w + p) * 16 + c16;
        bool writer = (j == 0) && (ptg < n);
        bool flag   = writer && (a2 - a1 <= EPS_GAP);
        unsigned long long m = __ballot(flag);
        int abase = 0;
        if (m) {
            int leader = __ffsll(m) - 1;
            if (l == leader) abase = atomicAdd(cnt, __popcll(m));
            abase = __shfl(abase, leader, 64);
        }
        if (writer) {
            int val = (int)(__float_as_uint(a1) & 0x1FFu);   // unpack argmin
            if (flag) {
                int rank = __popcll(m & ((1ull << l) - 1ull));
                int slot = abase + rank;
                if (slot < cap) list[slot] = ptg;       // worklist path
                else            val |= (int)0x80000000; // overflow fallback
            }
            out[ptg] = val;
        }
    }
}

// ---------- Pass 1 LEGACY (R13 verbatim, BM=128): used only if ws too small ----------
__global__ __launch_bounds__(256)
void vq_pass1_legacy(const float* __restrict__ z, const float* __restrict__ cb,
                     const float* __restrict__ norms, int* __restrict__ out,
                     int* __restrict__ cnt, int* __restrict__ list, int cap, int n) {
    __shared__ unsigned short zhS[128 * LSTR];
    __shared__ unsigned short zlS[128 * LSTR];
    __shared__ unsigned short ehS[128 * LSTR];
    __shared__ unsigned short elS[128 * LSTR];
    __shared__ float nrmL[128];

    const int tid  = threadIdx.x;
    const int l    = tid & 63;
    const int w    = tid >> 6;
    const int j    = l >> 4;
    const int c16  = l & 15;
    const int base = blockIdx.x * 128;

    const float4* z4 = reinterpret_cast<const float4*>(z);
#pragma unroll
    for (int rep = 0; rep < 8; ++rep) {
        int flat = rep * 256 + tid;
        int pt   = flat >> 4;
        int dblk = flat & 15;
        int gp = base + pt; if (gp >= n) gp = n - 1;
        float4 v = z4[(size_t)gp * 16 + dblk];
        ushort4 h, lo;
        split2(v.x, h.x, lo.x); split2(v.y, h.y, lo.y);
        split2(v.z, h.z, lo.z); split2(v.w, h.w, lo.w);
        *reinterpret_cast<ushort4*>(&zhS[pt * LSTR + dblk * 4]) = h;
        *reinterpret_cast<ushort4*>(&zlS[pt * LSTR + dblk * 4]) = lo;
    }
    __syncthreads();

    short8v bzh[2][2], bzl[2][2];
#pragma unroll
    for (int p = 0; p < 2; ++p) {
        int pr = ((2 * w + p) * 16 + c16) * LSTR;
#pragma unroll
        for (int h = 0; h < 2; ++h) {
            int off = pr + h * 32 + j * 8;
            bzh[p][h] = *reinterpret_cast<const short8v*>(&zhS[off]);
            bzl[p][h] = *reinterpret_cast<const short8v*>(&zlS[off]);
        }
    }

    float m1[2] = {INFINITY, INFINITY};
    float m2[2] = {INFINITY, INFINITY};
    int   i1[2] = {0, 0};

    for (int c = 0; c < 4; ++c) {
        __syncthreads();
        const float4* cb4 = reinterpret_cast<const float4*>(cb);
#pragma unroll
        for (int rep = 0; rep < 8; ++rep) {
            int flat = rep * 256 + tid;
            int code = flat >> 4;
            int dblk = flat & 15;
            float4 v = cb4[(size_t)(c * 128 + code) * 16 + dblk];
            ushort4 h, lo;
            split2(v.x, h.x, lo.x); split2(v.y, h.y, lo.y);
            split2(v.z, h.z, lo.z); split2(v.w, h.w, lo.w);
            *reinterpret_cast<ushort4*>(&ehS[code * LSTR + dblk * 4]) = h;
            *reinterpret_cast<ushort4*>(&elS[code * LSTR + dblk * 4]) = lo;
        }
        if (tid < 32)
            reinterpret_cast<float4*>(nrmL)[tid] =
                reinterpret_cast<const float4*>(norms)[c * 32 + tid];
        __syncthreads();

#pragma unroll
        for (int ct = 0; ct < 8; ++ct) {
            int ar = (ct * 16 + c16) * LSTR + j * 8;
            short8v aeh0 = *reinterpret_cast<const short8v*>(&ehS[ar]);
            short8v aeh1 = *reinterpret_cast<const short8v*>(&ehS[ar + 32]);
            short8v ael0 = *reinterpret_cast<const short8v*>(&elS[ar]);
            short8v ael1 = *reinterpret_cast<const short8v*>(&elS[ar + 32]);
            float4 nr = *reinterpret_cast<const float4*>(&nrmL[ct * 16 + j * 4]);
            float nra[4] = {nr.x, nr.y, nr.z, nr.w};
            int kg0 = c * 128 + ct * 16 + j * 4;
#pragma unroll
            for (int p = 0; p < 2; ++p) {
                f32x4 acc = {0.f, 0.f, 0.f, 0.f};
                acc = __builtin_amdgcn_mfma_f32_16x16x32_bf16(aeh0, bzh[p][0], acc, 0, 0, 0);
                acc = __builtin_amdgcn_mfma_f32_16x16x32_bf16(aeh1, bzh[p][1], acc, 0, 0, 0);
                acc = __builtin_amdgcn_mfma_f32_16x16x32_bf16(aeh0, bzl[p][0], acc, 0, 0, 0);
                acc = __builtin_amdgcn_mfma_f32_16x16x32_bf16(aeh1, bzl[p][1], acc, 0, 0, 0);
                acc = __builtin_amdgcn_mfma_f32_16x16x32_bf16(ael0, bzh[p][0], acc, 0, 0, 0);
                acc = __builtin_amdgcn_mfma_f32_16x16x32_bf16(ael1, bzh[p][1], acc, 0, 0, 0);
#pragma unroll
                for (int r = 0; r < 4; ++r) {
                    float s = fmaf(-2.0f, acc[r], nra[r]);
                    int kg = kg0 + r;
                    bool lt1 = s < m1[p];
                    float nm2 = lt1 ? m1[p] : fminf(s, m2[p]);
                    i1[p] = lt1 ? kg : i1[p];
                    m1[p] = lt1 ? s : m1[p];
                    m2[p] = nm2;
                }
            }
        }
    }

#pragma unroll
    for (int p = 0; p < 2; ++p) {
        float a1 = m1[p], a2 = m2[p]; int ai = i1[p];
#pragma unroll
        for (int off = 16; off <= 32; off <<= 1) {
            float o1 = __shfl_xor(a1, off, 64);
            float o2 = __shfl_xor(a2, off, 64);
            int   oi = __shfl_xor(ai, off, 64);
            float hi = fmaxf(a1, o1);
            bool take = o1 < a1;
            ai = take ? oi : ai;
            a1 = take ? o1 : a1;
            a2 = fminf(hi, fminf(a2, o2));
        }
        int  ptg    = base + (2 * w + p) * 16 + c16;
        bool writer = (j == 0) && (ptg < n);
        bool flag   = writer && (a2 - a1 <= EPS_GAP);
        unsigned long long m = __ballot(flag);
        int abase = 0;
        if (m) {
            int leader = __ffsll(m) - 1;
            if (l == leader) abase = atomicAdd(cnt, __popcll(m));
            abase = __shfl(abase, leader, 64);
        }
        if (writer) {
            int val = ai;
            if (flag) {
                int rank = __popcll(m & ((1ull << l) - 1ull));
                int slot = abase + rank;
                if (slot < cap) list[slot] = ptg;
                else            val |= (int)0x80000000;
            }
            out[ptg] = val;
        }
    }
}

// ---------- Pass 2 (R19's best-measured design): one BLOCK per flagged point ----------
// 2048 blocks, 4 waves x 2 codes/lane per point, codebook direct from L2
// (128 KB, resident). FROZEN chain; lexicographic reduce == first-min.
__global__ __launch_bounds__(256)
void vq_cleanup_kernel(const float* __restrict__ z, const float* __restrict__ cb,
                       const float* __restrict__ norms,
                       const int* __restrict__ cnt, const int* __restrict__ list,
                       int cap, int* __restrict__ out, int n) {
    __shared__ float rbv[4];
    __shared__ int   rbi[4];
    const int tid  = threadIdx.x;
    const int lane = tid & 63;
    const int wv   = tid >> 6;

    int total = *cnt;
    int lim   = total < cap ? total : cap;

    for (int i = blockIdx.x; i < lim; i += gridDim.x) {
        int pt = list[i];
        float zr[D_DIM];
        const float4* zp = reinterpret_cast<const float4*>(z + (size_t)pt * D_DIM);
#pragma unroll
        for (int g = 0; g < 16; ++g) {
            float4 q = zp[g];
            zr[4*g+0]=q.x; zr[4*g+1]=q.y; zr[4*g+2]=q.z; zr[4*g+3]=q.w;
        }
        const float sz = np_sumsq64(zr);           // FROZEN tree
        float best = INFINITY; int bi = 0x7FFFFFFF;
#pragma unroll 1
        for (int r = 0; r < 2; ++r) {              // 2 codes/thread, sequential
            int k = tid * 2 + r;
            const float4* e4 = reinterpret_cast<const float4*>(cb) + ((size_t)k << 4);
            float a = 0.f;
#pragma unroll
            for (int g = 0; g < 16; ++g) {         // FROZEN ascending-d chain
                float4 q = e4[g];
                a = fmaf(zr[4*g+0], q.x, a);
                a = fmaf(zr[4*g+1], q.y, a);
                a = fmaf(zr[4*g+2], q.z, a);
                a = fmaf(zr[4*g+3], q.w, a);
            }
            float s = __fadd_rn(__fsub_rn(sz, __fmul_rn(2.0f, a)), norms[k]);
            if (s < best || (s == best && k < bi)) { best = s; bi = k; }
        }
#pragma unroll
        for (int off = 1; off < 64; off <<= 1) {   // wave (value,index) reduce
            float os = __shfl_xor(best, off, 64);
            int   ok = __shfl_xor(bi, off, 64);
            if (os < best || (os == best && ok < bi)) { best = os; bi = ok; }
        }
        if (lane == 0) { rbv[wv] = best; rbi[wv] = bi; }
        __syncthreads();
        if (tid == 0) {
            float b = rbv[0]; int id = rbi[0];
#pragma unroll
            for (int q = 1; q < 4; ++q) {
                float v = rbv[q]; int vi = rbi[q];
                if (v < b || (v == b && vi < id)) { b = v; id = vi; }
            }
            out[pt] = id;
        }
        __syncthreads();
    }

    // overflow fallback: wave-per-point scan of out[] for bit-31 flags
    if (total > cap) {
        const int wid    = (blockIdx.x * blockDim.x + tid) >> 6;
        const int nwaves = (gridDim.x * blockDim.x) >> 6;
        for (int b = wid * 64; b < n; b += nwaves * 64) {
            int t = b + lane;
            int v = (t < n) ? out[t] : 0;
            unsigned long long m = __ballot(v < 0);
            while (m) {
                int bb = __ffsll(m) - 1;
                m &= m - 1ull;
                int pt = b + bb;
                float zr[D_DIM];
                const float4* zp = reinterpret_cast<const float4*>(z + (size_t)pt * D_DIM);
#pragma unroll
                for (int g = 0; g < 16; ++g) {
                    float4 q = zp[g];
                    zr[4*g+0]=q.x; zr[4*g+1]=q.y; zr[4*g+2]=q.z; zr[4*g+3]=q.w;
                }
                const float sz = np_sumsq64(zr);
                float best = INFINITY; int bi = 0x7FFFFFFF;
#pragma unroll 1
                for (int r = 0; r < 8; ++r) {
                    const float4* e4 = reinterpret_cast<const float4*>(cb) +
                                       ((size_t)(lane * 8 + r) << 4);
                    float a = 0.f;
#pragma unroll
                    for (int g = 0; g < 16; ++g) {
                        float4 q = e4[g];
                        a = fmaf(zr[4*g+0], q.x, a);
                        a = fmaf(zr[4*g+1], q.y, a);
                        a = fmaf(zr[4*g+2], q.z, a);
                        a = fmaf(zr[4*g+3], q.w, a);
                    }
                    float s = __fadd_rn(__fsub_rn(sz, __fmul_rn(2.0f, a)),
                                        norms[lane * 8 + r]);
                    if (s < best) { best = s; bi = lane * 8 + r; }
                }
#pragma unroll
                for (int off = 1; off < 64; off <<= 1) {
                    float os = __shfl_xor(best, off, 64);
                    int   ok = __shfl_xor(bi, off, 64);
                    if (os < best || (os == best && ok < bi)) { best = os; bi = ok; }
                }
                if (lane == 0) out[pt] = bi;
            }
        }
    }
}

extern "C" void kernel_launch(void* const* d_in, const int* in_sizes, int n_in,
                              void* d_out, int out_size, void* d_ws, size_t ws_size,
                              hipStream_t stream) {
    const float* z  = (const float*)d_in[0];
    const float* cb = (const float*)d_in[1];
    int n = in_sizes[0] / D_DIM;           // 131072 points
    float* norms = (float*)d_ws;
    int*   cnt   = (int*)((char*)d_ws + WS_CNT_OFF);
    int* out = (int*)d_out;

    bool fast = ws_size >= (size_t)WS_LIST_OFF + 4096;
    vq_prep_kernel<<<(4 * K_CODES + 255) / 256, 256, 0, stream>>>(cb, norms, fast ? 1 : 0);

    if (fast) {
        const unsigned short* eh = (const unsigned short*)((char*)d_ws + WS_EH_OFF);
        const unsigned short* el = (const unsigned short*)((char*)d_ws + WS_EL_OFF);
        int* list = (int*)((char*)d_ws + WS_LIST_OFF);
        int  cap  = (int)((ws_size - WS_LIST_OFF) / 4);
        vq_pass1_mono<<<(n + BM - 1) / BM, THREADS, 0, stream>>>(
            z, eh, el, norms, out, cnt, list, cap, n);
        vq_cleanup_kernel<<<2048, 256, 0, stream>>>(z, cb, norms, cnt, list, cap, out, n);
    } else {
        int* list = (int*)d_ws + 513;
        int  cap  = (int)(ws_size / 4) - 513; if (cap < 0) cap = 0;
        vq_pass1_legacy<<<(n + 127) / 128, 256, 0, stream>>>(
            z, cb, norms, out, cnt, list, cap, n);
        vq_cleanup_kernel<<<2048, 256, 0, stream>>>(z, cb, norms, cnt, list, cap, out, n);
    }
}